// Round 1
// baseline (528.334 us; speedup 1.0000x reference)
//
#include <hip/hip_runtime.h>
#include <math.h>

#define N 8192
#define C 64
#define WSP (N*8 + N*8 + N*C)   // per-attend workspace floats: f + gT + v(t)

// ---------------------------------------------------------------------------
// Kernel 0: projections. out[n][o] = sum_c W[o][c] * x[c][n] + b[o]
// o in [0,8): f, [8,16): gT, [16,80): v.  One block per 64-column n-tile.
// ---------------------------------------------------------------------------
__global__ __launch_bounds__(256) void prep_kernel(
    const float* __restrict__ x1, const float* __restrict__ x2,
    const float* __restrict__ Wf, const float* __restrict__ bf,
    const float* __restrict__ Wg, const float* __restrict__ bg,
    const float* __restrict__ Wh1, const float* __restrict__ bh1,
    const float* __restrict__ Wh2, const float* __restrict__ bh2,
    float* __restrict__ ws)
{
    const int a = blockIdx.y;
    const float* x  = a ? x2  : x1;
    const float* Wh = a ? Wh2 : Wh1;
    const float* bh = a ? bh2 : bh1;
    float* f  = ws + (size_t)a * WSP;   // [N][8]
    float* gt = f + N*8;                // [N][8]  (g transposed: gt[m][k])
    float* vb = gt + N*8;               // [N][64]

    __shared__ float xs[64][65];        // +1 pad: column reads conflict-free
    const int n0 = blockIdx.x * 64;
    const int t  = threadIdx.x;
    for (int i = t; i < 64*64; i += 256) {
        int c = i >> 6, j = i & 63;
        xs[c][j] = x[(size_t)c*N + n0 + j];
    }
    __syncthreads();

    const int j  = t & 63;   // n within tile (coalesced across lanes)
    const int og = t >> 6;   // 0..3, wave-uniform: o = og + 4k
    float s[20];
    const float* wrow[20];
    #pragma unroll
    for (int k = 0; k < 20; ++k) {
        int o = og + 4*k;
        if (o < 8)       { wrow[k] = Wf + o*64;      s[k] = bf[o];      }
        else if (o < 16) { wrow[k] = Wg + (o-8)*64;  s[k] = bg[o-8];    }
        else             { wrow[k] = Wh + (o-16)*64; s[k] = bh[o-16];   }
    }
    #pragma unroll 8
    for (int c = 0; c < 64; ++c) {
        float xc = xs[c][j];
        #pragma unroll
        for (int k = 0; k < 20; ++k) s[k] += wrow[k][c] * xc;
    }
    #pragma unroll
    for (int k = 0; k < 20; ++k) {
        int o = og + 4*k;
        if (o < 8)       f [(size_t)(n0+j)*8  + o]      = s[k];
        else if (o < 16) gt[(size_t)(n0+j)*8  + (o-8)]  = s[k];
        else             vb[(size_t)(n0+j)*64 + (o-16)] = s[k];
    }
}

// ---------------------------------------------------------------------------
// Kernel 1: l[n] = sum_m exp(f[n].gt[m]); then vt[n][c] = v[n][c] / l[n].
// 8 rows per block; f rows in registers; gt streamed coalesced (float4 x2).
// ---------------------------------------------------------------------------
__global__ __launch_bounds__(256) void rownorm_kernel(float* __restrict__ ws)
{
    const int a = blockIdx.y;
    float* f  = ws + (size_t)a * WSP;
    float* gt = f + N*8;
    float* vb = gt + N*8;
    const int n0 = blockIdx.x * 8;
    const int t  = threadIdx.x;

    __shared__ float fs[64];
    __shared__ float red[8][4];
    __shared__ float linv[8];
    if (t < 64) fs[t] = f[(size_t)n0*8 + t];
    __syncthreads();
    float fr[8][8];
    #pragma unroll
    for (int r = 0; r < 8; ++r) {
        #pragma unroll
        for (int k = 0; k < 8; ++k) fr[r][k] = fs[r*8+k];
    }

    float l[8] = {0,0,0,0,0,0,0,0};
    for (int m = t; m < N; m += 256) {
        const float4 ga = *(const float4*)(gt + (size_t)m*8);
        const float4 gb = *(const float4*)(gt + (size_t)m*8 + 4);
        #pragma unroll
        for (int r = 0; r < 8; ++r) {
            float s = fr[r][0]*ga.x + fr[r][1]*ga.y + fr[r][2]*ga.z + fr[r][3]*ga.w
                    + fr[r][4]*gb.x + fr[r][5]*gb.y + fr[r][6]*gb.z + fr[r][7]*gb.w;
            l[r] += __expf(s);
        }
    }
    #pragma unroll
    for (int r = 0; r < 8; ++r) {
        float v = l[r];
        #pragma unroll
        for (int off = 32; off > 0; off >>= 1) v += __shfl_down(v, off, 64);
        if ((t & 63) == 0) red[r][t >> 6] = v;
    }
    __syncthreads();
    if (t < 8) linv[t] = 1.0f / (red[t][0] + red[t][1] + red[t][2] + red[t][3]);
    __syncthreads();
    for (int i = t; i < 8*64; i += 256) {
        vb[(size_t)n0*64 + i] *= linv[i >> 6];
    }
}

// ---------------------------------------------------------------------------
// Kernel 2: sa[c][m] = sum_n vt[n][c] * exp(f[n].g[m]);  out = gamma*sa + x.
// One block per 64-col m-tile; 4 waves take interleaved 16-row n-chunks;
// 8x8 register blocking (1 byte LDS / FMA); LDS cross-wave reduce at end.
// ---------------------------------------------------------------------------
#define TN 16
__global__ __launch_bounds__(256) void attn_out_kernel(
    const float* __restrict__ x1, const float* __restrict__ x2,
    const float* __restrict__ g1, const float* __restrict__ g2,
    const float* __restrict__ ws, float* __restrict__ out_)
{
    const int a = blockIdx.y;
    const float* x = a ? x2 : x1;
    const float gamma = a ? g2[0] : g1[0];
    const float* f  = ws + (size_t)a * WSP;
    const float* gt = f + N*8;
    const float* vt = gt + N*8;
    float* out = out_ + (size_t)a * ((size_t)C*N);

    const int m0   = blockIdx.x * 64;
    const int t    = threadIdx.x;
    const int w    = t >> 6;
    const int lane = t & 63;
    const int cg   = lane >> 3;   // c octet
    const int mg   = lane & 7;    // m octet

    __shared__ float vt_s[4][TN][64];
    __shared__ float p_s [4][TN][64];
    __shared__ float red [64][65];

    // this lane's g fragment (column m0+lane), lives in registers all kernel
    const float4 ga = *(const float4*)(gt + (size_t)(m0+lane)*8);
    const float4 gb = *(const float4*)(gt + (size_t)(m0+lane)*8 + 4);

    float acc[8][8];
    #pragma unroll
    for (int i = 0; i < 8; ++i) {
        #pragma unroll
        for (int k = 0; k < 8; ++k) acc[i][k] = 0.f;
    }

    for (int chunk = w; chunk < N/TN; chunk += 4) {
        const int n0 = chunk * TN;
        // stage vt chunk: 16 rows x 64 c, contiguous 1024 floats, float4 coalesced
        {
            const float4* src = (const float4*)(vt + (size_t)n0*64);
            float4* dst = (float4*)&vt_s[w][0][0];
            #pragma unroll
            for (int i = 0; i < 4; ++i) dst[i*64 + lane] = src[i*64 + lane];
        }
        // p rows: lane computes column m0+lane for all 16 n's
        #pragma unroll
        for (int r = 0; r < TN; ++r) {
            const float4 fa = *(const float4*)(f + (size_t)(n0+r)*8);
            const float4 fb = *(const float4*)(f + (size_t)(n0+r)*8 + 4);
            float s = fa.x*ga.x + fa.y*ga.y + fa.z*ga.z + fa.w*ga.w
                    + fb.x*gb.x + fb.y*gb.y + fb.z*gb.z + fb.w*gb.w;
            p_s[w][r][lane] = __expf(s);
        }
        __syncthreads();
        // rank-TN update: 64 FMA per 64B of LDS
        #pragma unroll
        for (int r = 0; r < TN; ++r) {
            const float4 va  = *(const float4*)&vt_s[w][r][cg*8];
            const float4 vb4 = *(const float4*)&vt_s[w][r][cg*8+4];
            const float4 pa  = *(const float4*)&p_s[w][r][mg*8];
            const float4 pb  = *(const float4*)&p_s[w][r][mg*8+4];
            const float vv[8] = {va.x,va.y,va.z,va.w,vb4.x,vb4.y,vb4.z,vb4.w};
            const float pp[8] = {pa.x,pa.y,pa.z,pa.w,pb.x,pb.y,pb.z,pb.w};
            #pragma unroll
            for (int ci = 0; ci < 8; ++ci) {
                #pragma unroll
                for (int mi = 0; mi < 8; ++mi)
                    acc[ci][mi] += vv[ci] * pp[mi];
            }
        }
        __syncthreads();
    }

    // cross-wave reduction of the 64x64 tile
    for (int ww = 0; ww < 4; ++ww) {
        if (w == ww) {
            #pragma unroll
            for (int ci = 0; ci < 8; ++ci) {
                #pragma unroll
                for (int mi = 0; mi < 8; ++mi) {
                    if (ww == 0) red[cg*8+ci][mg*8+mi]  = acc[ci][mi];
                    else         red[cg*8+ci][mg*8+mi] += acc[ci][mi];
                }
            }
        }
        __syncthreads();
    }
    // epilogue: out[c][m] = gamma*sa + x, coalesced over m
    for (int i = t; i < 64*64; i += 256) {
        int c = i >> 6, j = i & 63;
        size_t gi = (size_t)c*N + m0 + j;
        out[gi] = gamma * red[c][j] + x[gi];
    }
}

// ---------------------------------------------------------------------------
extern "C" void kernel_launch(void* const* d_in, const int* in_sizes, int n_in,
                              void* d_out, int out_size, void* d_ws, size_t ws_size,
                              hipStream_t stream)
{
    (void)in_sizes; (void)n_in; (void)out_size; (void)ws_size;
    const float* x1  = (const float*)d_in[0];
    const float* x2  = (const float*)d_in[1];
    const float* Wf  = (const float*)d_in[2];
    const float* bf  = (const float*)d_in[3];
    const float* Wg  = (const float*)d_in[4];
    const float* bg  = (const float*)d_in[5];
    const float* Wh1 = (const float*)d_in[6];
    const float* bh1 = (const float*)d_in[7];
    const float* Wh2 = (const float*)d_in[8];
    const float* bh2 = (const float*)d_in[9];
    const float* g1  = (const float*)d_in[10];
    const float* g2  = (const float*)d_in[11];
    float* out = (float*)d_out;
    float* ws  = (float*)d_ws;

    dim3 blk(256);
    prep_kernel   <<<dim3(N/64, 2), blk, 0, stream>>>(x1,x2,Wf,bf,Wg,bg,Wh1,bh1,Wh2,bh2,ws);
    rownorm_kernel<<<dim3(N/8,  2), blk, 0, stream>>>(ws);
    attn_out_kernel<<<dim3(N/64, 2), blk, 0, stream>>>(x1,x2,g1,g2,ws,out);
}

// Round 2
// 316.043 us; speedup vs baseline: 1.6717x; 1.6717x over previous
//
#include <hip/hip_runtime.h>
#include <math.h>

#define N 8192
#define WSP (80*N)          // per-attend workspace floats
#define OFF_G (8*N)         // g[m][8]
#define OFF_T (16*N)        // vb fp32 (prep) -> per-chunk bf16 hi/lo tiles (rownorm)
// tile layout after rownorm: per 32-row chunk b (floats [OFF_T+2048b, +2048)):
//   ushort tileH[64][32] (A-frag rows: tile[c][kk] = vt[n0+kk][c]), then ushort tileL[64][32]

typedef __attribute__((ext_vector_type(8))) short bf16x8;
typedef __attribute__((ext_vector_type(4))) float f32x4;

#if defined(__has_builtin)
#  if __has_builtin(__builtin_amdgcn_exp2f)
#    define EXP2(x) __builtin_amdgcn_exp2f(x)
#  endif
#endif
#ifndef EXP2
#  define EXP2(x) exp2f(x)
#endif

__device__ __forceinline__ unsigned short bf_hi(float x) {
    union { float f; unsigned u; } v; v.f = x;
    unsigned r = v.u + 0x7fffu + ((v.u >> 16) & 1u);   // round-to-nearest-even
    return (unsigned short)(r >> 16);
}
__device__ __forceinline__ float bf_f(unsigned short h) {
    union { float f; unsigned u; } v; v.u = ((unsigned)h) << 16;
    return v.f;
}

// ---------------------------------------------------------------------------
// Kernel 0: projections. f is pre-scaled by log2(e) so attention exps are
// bare v_exp_f32 (exp2) downstream.
// ---------------------------------------------------------------------------
__global__ __launch_bounds__(256) void prep_kernel(
    const float* __restrict__ x1, const float* __restrict__ x2,
    const float* __restrict__ Wf, const float* __restrict__ bf,
    const float* __restrict__ Wg, const float* __restrict__ bg,
    const float* __restrict__ Wh1, const float* __restrict__ bh1,
    const float* __restrict__ Wh2, const float* __restrict__ bh2,
    float* __restrict__ ws)
{
    const int a = blockIdx.y;
    const float* x  = a ? x2  : x1;
    const float* Wh = a ? Wh2 : Wh1;
    const float* bh = a ? bh2 : bh1;
    float* f2 = ws + (size_t)a * WSP;   // [N][8], scaled by log2e
    float* gt = f2 + OFF_G;             // [N][8]
    float* vb = f2 + OFF_T;             // [N][64] fp32 (consumed by rownorm)

    __shared__ float xs[64][65];
    const int n0 = blockIdx.x * 64;
    const int t  = threadIdx.x;
    for (int i = t; i < 64*64; i += 256) {
        int c = i >> 6, j = i & 63;
        xs[c][j] = x[(size_t)c*N + n0 + j];
    }
    __syncthreads();

    const int j  = t & 63;
    const int og = t >> 6;
    float s[20];
    const float* wrow[20];
    #pragma unroll
    for (int k = 0; k < 20; ++k) {
        int o = og + 4*k;
        if (o < 8)       { wrow[k] = Wf + o*64;      s[k] = bf[o];      }
        else if (o < 16) { wrow[k] = Wg + (o-8)*64;  s[k] = bg[o-8];    }
        else             { wrow[k] = Wh + (o-16)*64; s[k] = bh[o-16];   }
    }
    #pragma unroll 8
    for (int c = 0; c < 64; ++c) {
        float xc = xs[c][j];
        #pragma unroll
        for (int k = 0; k < 20; ++k) s[k] += wrow[k][c] * xc;
    }
    const float LOG2E = 1.44269504088896340736f;
    #pragma unroll
    for (int k = 0; k < 20; ++k) {
        int o = og + 4*k;
        if (o < 8)       f2[(size_t)(n0+j)*8  + o]      = s[k] * LOG2E;
        else if (o < 16) gt[(size_t)(n0+j)*8  + (o-8)]  = s[k];
        else             vb[(size_t)(n0+j)*64 + (o-16)] = s[k];
    }
}

// ---------------------------------------------------------------------------
// Kernel 1: per-row softmax denominator l[n] = sum_m exp2(f2[n].g[m]); then
// convert vt = v/l to bf16 hi/lo A-fragment tiles IN PLACE over vb.
// One block per 32-row chunk (owns its tile region exclusively).
// ---------------------------------------------------------------------------
__global__ __launch_bounds__(256) void rownorm_kernel(float* __restrict__ ws)
{
    const int a = blockIdx.y;
    float* f2 = ws + (size_t)a * WSP;
    float* gg = f2 + OFF_G;
    float* vb = f2 + OFF_T;
    const int n0 = blockIdx.x * 32;
    const int t  = threadIdx.x;
    const int w = t >> 6, lane = t & 63;

    __shared__ float vbs[32][64];   // staged v rows (so in-place overwrite is safe)
    __shared__ float fs[256];
    __shared__ float linv[32];

    #pragma unroll
    for (int i = 0; i < 8; ++i) {
        int e = t + 256*i;
        vbs[e >> 6][e & 63] = vb[(size_t)n0*64 + e];
    }
    fs[t] = f2[(size_t)n0*8 + t];
    __syncthreads();

    // wave w owns rows n0 + 8w .. +8
    float fr[8][8];
    #pragma unroll
    for (int r = 0; r < 8; ++r)
        #pragma unroll
        for (int i = 0; i < 8; ++i) fr[r][i] = fs[(w*8+r)*8 + i];

    float l[8] = {0,0,0,0,0,0,0,0};
    for (int m = lane; m < N; m += 64) {
        const float4 ga = *(const float4*)(gg + (size_t)m*8);
        const float4 gb = *(const float4*)(gg + (size_t)m*8 + 4);
        #pragma unroll
        for (int r = 0; r < 8; ++r) {
            float s = fr[r][0]*ga.x + fr[r][1]*ga.y + fr[r][2]*ga.z + fr[r][3]*ga.w
                    + fr[r][4]*gb.x + fr[r][5]*gb.y + fr[r][6]*gb.z + fr[r][7]*gb.w;
            l[r] += EXP2(s);
        }
    }
    #pragma unroll
    for (int r = 0; r < 8; ++r) {
        float v = l[r];
        #pragma unroll
        for (int off = 32; off; off >>= 1) v += __shfl_xor(v, off, 64);
        if (lane == 0) linv[w*8 + r] = 1.0f / v;
    }
    __syncthreads();

    // phase 3: thread t -> (c = t&63, k-octet kkg = t>>6); one 16B store per array
    const int c = t & 63, kkg = t >> 6;
    bf16x8 H, L;
    #pragma unroll
    for (int jj = 0; jj < 8; ++jj) {
        int kk = kkg*8 + jj;
        float v = vbs[kk][c] * linv[kk];
        unsigned short h = bf_hi(v);
        H[jj] = (short)h;
        L[jj] = (short)bf_hi(v - bf_f(h));
    }
    unsigned short* tile = (unsigned short*)(f2 + OFF_T) + (size_t)(n0 >> 5) * 4096;
    unsigned short* tp = tile + c*32 + kkg*8;
    *(bf16x8*)tp          = H;
    *(bf16x8*)(tp + 2048) = L;
}

// ---------------------------------------------------------------------------
// Kernel 2: sa[c][m] = sum_n vt[n][c] * exp2(f2[n].g[m]) via MFMA bf16 hi/lo.
// wg = 4 waves; each wave: full 64c x 64m tile, 1/4 of K. No LDS / no barrier
// in the K-loop; A-frags read straight from L2-resident tiles; p computed
// in B-fragment layout in-registers (B[k=quad*8+j][m=lane&15]).
// ---------------------------------------------------------------------------
__global__ __launch_bounds__(256, 1) void attn_kernel(
    const float* __restrict__ x1, const float* __restrict__ x2,
    const float* __restrict__ ga1, const float* __restrict__ ga2,
    const float* __restrict__ ws, float* __restrict__ out_)
{
    const int a = blockIdx.y;
    const float* x = a ? x2 : x1;
    const float gamma = a ? ga2[0] : ga1[0];
    const float* f2 = ws + (size_t)a * WSP;
    const float* gg = f2 + OFF_G;
    const unsigned short* tiles = (const unsigned short*)(f2 + OFF_T);
    float* out = out_ + (size_t)a * ((size_t)64 * N);

    const int m0 = blockIdx.x * 64;
    const int t = threadIdx.x;
    const int w = t >> 6, lane = t & 63;
    const int quad = lane >> 4, l15 = lane & 15;

    // g fragments: lane's 4 m-columns, resident all kernel
    float4 gA[4], gB[4];
    #pragma unroll
    for (int mt = 0; mt < 4; ++mt) {
        const float* gp = gg + (size_t)(m0 + mt*16 + l15) * 8;
        gA[mt] = *(const float4*)gp;
        gB[mt] = *(const float4*)(gp + 4);
    }

    f32x4 acc[4][4];   // [ct][mt]
    #pragma unroll
    for (int i = 0; i < 4; ++i)
        #pragma unroll
        for (int k = 0; k < 4; ++k) acc[i][k] = (f32x4){0.f,0.f,0.f,0.f};

    const int kbeg = w * (N/4);
    const int kend = kbeg + (N/4);

    float4 fA[2][8], fB[2][8];
    bf16x8 Ah[2][4], Al[2][4];

    auto load_step = [&](int k0, int b) {
        const float* fp = f2 + (size_t)(k0 + quad*8) * 8;
        #pragma unroll
        for (int j = 0; j < 8; ++j) {
            fA[b][j] = *(const float4*)(fp + j*8);
            fB[b][j] = *(const float4*)(fp + j*8 + 4);
        }
        const unsigned short* tb = tiles + (size_t)(k0 >> 5) * 4096 + quad*8;
        #pragma unroll
        for (int ct = 0; ct < 4; ++ct) {
            const unsigned short* tc = tb + (ct*16 + l15) * 32;
            Ah[b][ct] = *(const bf16x8*)tc;
            Al[b][ct] = *(const bf16x8*)(tc + 2048);
        }
    };
    auto compute = [&](int b) {
        #pragma unroll
        for (int mt = 0; mt < 4; ++mt) {
            bf16x8 Bh, Bl;
            #pragma unroll
            for (int j = 0; j < 8; ++j) {
                const float4 fa = fA[b][j], fb = fB[b][j];
                float s = fa.x*gA[mt].x + fa.y*gA[mt].y + fa.z*gA[mt].z + fa.w*gA[mt].w
                        + fb.x*gB[mt].x + fb.y*gB[mt].y + fb.z*gB[mt].z + fb.w*gB[mt].w;
                float p = EXP2(s);
                unsigned short h = bf_hi(p);
                Bh[j] = (short)h;
                Bl[j] = (short)bf_hi(p - bf_f(h));
            }
            #pragma unroll
            for (int ct = 0; ct < 4; ++ct) {
                acc[ct][mt] = __builtin_amdgcn_mfma_f32_16x16x32_bf16(Ah[b][ct], Bh, acc[ct][mt], 0, 0, 0);
                acc[ct][mt] = __builtin_amdgcn_mfma_f32_16x16x32_bf16(Ah[b][ct], Bl, acc[ct][mt], 0, 0, 0);
                acc[ct][mt] = __builtin_amdgcn_mfma_f32_16x16x32_bf16(Al[b][ct], Bh, acc[ct][mt], 0, 0, 0);
            }
        }
    };

    load_step(kbeg, 0);
    for (int k0 = kbeg; k0 < kend; k0 += 64) {
        load_step(k0 + 32, 1);
        compute(0);
        if (k0 + 64 < kend) load_step(k0 + 64, 0);
        compute(1);
    }

    // cross-wave (K-split) reduction
    __shared__ float red[64][65];
    for (int ww = 0; ww < 4; ++ww) {
        if (w == ww) {
            #pragma unroll
            for (int ct = 0; ct < 4; ++ct)
                #pragma unroll
                for (int mt = 0; mt < 4; ++mt)
                    #pragma unroll
                    for (int r = 0; r < 4; ++r) {
                        int c = ct*16 + quad*4 + r;      // C/D: row=(lane>>4)*4+reg
                        int m = mt*16 + l15;             //      col=lane&15
                        if (ww == 0) red[c][m]  = acc[ct][mt][r];
                        else         red[c][m] += acc[ct][mt][r];
                    }
        }
        __syncthreads();
    }
    #pragma unroll
    for (int i = 0; i < 16; ++i) {
        int e = t + 256*i;
        int c = e >> 6, m = e & 63;
        size_t gi = (size_t)c*N + m0 + m;
        out[gi] = gamma * red[c][m] + x[gi];
    }
}

// ---------------------------------------------------------------------------
extern "C" void kernel_launch(void* const* d_in, const int* in_sizes, int n_in,
                              void* d_out, int out_size, void* d_ws, size_t ws_size,
                              hipStream_t stream)
{
    (void)in_sizes; (void)n_in; (void)out_size; (void)ws_size;
    const float* x1  = (const float*)d_in[0];
    const float* x2  = (const float*)d_in[1];
    const float* Wf  = (const float*)d_in[2];
    const float* bf  = (const float*)d_in[3];
    const float* Wg  = (const float*)d_in[4];
    const float* bg  = (const float*)d_in[5];
    const float* Wh1 = (const float*)d_in[6];
    const float* bh1 = (const float*)d_in[7];
    const float* Wh2 = (const float*)d_in[8];
    const float* bh2 = (const float*)d_in[9];
    const float* g1  = (const float*)d_in[10];
    const float* g2  = (const float*)d_in[11];
    float* out = (float*)d_out;
    float* ws  = (float*)d_ws;

    dim3 blk(256);
    prep_kernel   <<<dim3(N/64, 2), blk, 0, stream>>>(x1,x2,Wf,bf,Wg,bg,Wh1,bh1,Wh2,bh2,ws);
    rownorm_kernel<<<dim3(N/32, 2), blk, 0, stream>>>(ws);
    attn_kernel   <<<dim3(N/64, 2), blk, 0, stream>>>(x1,x2,g1,g2,ws,out);
}

// Round 3
// 281.210 us; speedup vs baseline: 1.8788x; 1.1239x over previous
//
#include <hip/hip_runtime.h>
#include <math.h>

#define N 8192
#define WSP (80*N)          // per-attend workspace floats
#define OFF_G (8*N)         // g[m][8]
#define OFF_T (16*N)        // vb fp32 (prep) -> per-chunk bf16 hi/lo tiles (rownorm)
// tile layout after rownorm: per 32-row chunk b (floats [OFF_T+2048b, +2048)):
//   ushort tileH[64][32] (A-frag rows: tile[c][kk] = vt[n0+kk][c]), then ushort tileL[64][32]

typedef __attribute__((ext_vector_type(8))) short bf16x8;
typedef __attribute__((ext_vector_type(4))) float f32x4;

#if defined(__has_builtin)
#  if __has_builtin(__builtin_amdgcn_exp2f)
#    define EXP2(x) __builtin_amdgcn_exp2f(x)
#  endif
#endif
#ifndef EXP2
#  define EXP2(x) exp2f(x)
#endif

__device__ __forceinline__ unsigned short bf_hi(float x) {
    union { float f; unsigned u; } v; v.f = x;
    unsigned r = v.u + 0x7fffu + ((v.u >> 16) & 1u);   // round-to-nearest-even
    return (unsigned short)(r >> 16);
}
__device__ __forceinline__ float bf_f(unsigned short h) {
    union { float f; unsigned u; } v; v.u = ((unsigned)h) << 16;
    return v.f;
}

// ---------------------------------------------------------------------------
// Kernel 0: projections. f is pre-scaled by log2(e) so attention exps are
// bare v_exp_f32 (exp2) downstream.
// ---------------------------------------------------------------------------
__global__ __launch_bounds__(256) void prep_kernel(
    const float* __restrict__ x1, const float* __restrict__ x2,
    const float* __restrict__ Wf, const float* __restrict__ bf,
    const float* __restrict__ Wg, const float* __restrict__ bg,
    const float* __restrict__ Wh1, const float* __restrict__ bh1,
    const float* __restrict__ Wh2, const float* __restrict__ bh2,
    float* __restrict__ ws)
{
    const int a = blockIdx.y;
    const float* x  = a ? x2  : x1;
    const float* Wh = a ? Wh2 : Wh1;
    const float* bh = a ? bh2 : bh1;
    float* f2 = ws + (size_t)a * WSP;   // [N][8], scaled by log2e
    float* gt = f2 + OFF_G;             // [N][8]
    float* vb = f2 + OFF_T;             // [N][64] fp32 (consumed by rownorm)

    __shared__ float xs[64][65];
    const int n0 = blockIdx.x * 64;
    const int t  = threadIdx.x;
    for (int i = t; i < 64*64; i += 256) {
        int c = i >> 6, j = i & 63;
        xs[c][j] = x[(size_t)c*N + n0 + j];
    }
    __syncthreads();

    const int j  = t & 63;
    const int og = t >> 6;
    float s[20];
    const float* wrow[20];
    #pragma unroll
    for (int k = 0; k < 20; ++k) {
        int o = og + 4*k;
        if (o < 8)       { wrow[k] = Wf + o*64;      s[k] = bf[o];      }
        else if (o < 16) { wrow[k] = Wg + (o-8)*64;  s[k] = bg[o-8];    }
        else             { wrow[k] = Wh + (o-16)*64; s[k] = bh[o-16];   }
    }
    #pragma unroll 8
    for (int c = 0; c < 64; ++c) {
        float xc = xs[c][j];
        #pragma unroll
        for (int k = 0; k < 20; ++k) s[k] += wrow[k][c] * xc;
    }
    const float LOG2E = 1.44269504088896340736f;
    #pragma unroll
    for (int k = 0; k < 20; ++k) {
        int o = og + 4*k;
        if (o < 8)       f2[(size_t)(n0+j)*8  + o]      = s[k] * LOG2E;
        else if (o < 16) gt[(size_t)(n0+j)*8  + (o-8)]  = s[k];
        else             vb[(size_t)(n0+j)*64 + (o-16)] = s[k];
    }
}

// ---------------------------------------------------------------------------
// Kernel 1: per-row softmax denominator l[n] = sum_m exp2(f2[n].g[m]); then
// convert vt = v/l to bf16 hi/lo A-fragment tiles IN PLACE over vb.
// One block per 32-row chunk (owns its tile region exclusively).
// ---------------------------------------------------------------------------
__global__ __launch_bounds__(256) void rownorm_kernel(float* __restrict__ ws)
{
    const int a = blockIdx.y;
    float* f2 = ws + (size_t)a * WSP;
    float* gg = f2 + OFF_G;
    float* vb = f2 + OFF_T;
    const int n0 = blockIdx.x * 32;
    const int t  = threadIdx.x;
    const int w = t >> 6, lane = t & 63;

    __shared__ float vbs[32][64];   // staged v rows (so in-place overwrite is safe)
    __shared__ float fs[256];
    __shared__ float linv[32];

    #pragma unroll
    for (int i = 0; i < 8; ++i) {
        int e = t + 256*i;
        vbs[e >> 6][e & 63] = vb[(size_t)n0*64 + e];
    }
    fs[t] = f2[(size_t)n0*8 + t];
    __syncthreads();

    // wave w owns rows n0 + 8w .. +8
    float fr[8][8];
    #pragma unroll
    for (int r = 0; r < 8; ++r)
        #pragma unroll
        for (int i = 0; i < 8; ++i) fr[r][i] = fs[(w*8+r)*8 + i];

    float l[8] = {0,0,0,0,0,0,0,0};
    for (int m = lane; m < N; m += 64) {
        const float4 ga = *(const float4*)(gg + (size_t)m*8);
        const float4 gb = *(const float4*)(gg + (size_t)m*8 + 4);
        #pragma unroll
        for (int r = 0; r < 8; ++r) {
            float s = fr[r][0]*ga.x + fr[r][1]*ga.y + fr[r][2]*ga.z + fr[r][3]*ga.w
                    + fr[r][4]*gb.x + fr[r][5]*gb.y + fr[r][6]*gb.z + fr[r][7]*gb.w;
            l[r] += EXP2(s);
        }
    }
    #pragma unroll
    for (int r = 0; r < 8; ++r) {
        float v = l[r];
        #pragma unroll
        for (int off = 32; off; off >>= 1) v += __shfl_xor(v, off, 64);
        if (lane == 0) linv[w*8 + r] = 1.0f / v;
    }
    __syncthreads();

    // phase 3: thread t -> (c = t&63, k-octet kkg = t>>6); one 16B store per array
    const int c = t & 63, kkg = t >> 6;
    bf16x8 H, L;
    #pragma unroll
    for (int jj = 0; jj < 8; ++jj) {
        int kk = kkg*8 + jj;
        float v = vbs[kk][c] * linv[kk];
        unsigned short h = bf_hi(v);
        H[jj] = (short)h;
        L[jj] = (short)bf_hi(v - bf_f(h));
    }
    unsigned short* tile = (unsigned short*)(f2 + OFF_T) + (size_t)(n0 >> 5) * 4096;
    unsigned short* tp = tile + c*32 + kkg*8;
    *(bf16x8*)tp          = H;
    *(bf16x8*)(tp + 2048) = L;
}

// ---------------------------------------------------------------------------
// Kernel 2: sa[c][m] = sum_n vt[n][c] * exp2(f2[n].g[m]) via MFMA bf16 hi/lo.
// 512 threads = 8 waves; each wave: full 64c x 64m tile, 1/8 of K; 2 waves/SIMD
// so VALU(p-compute) overlaps MFMA + load latency across waves. No LDS/barrier
// in the K-loop. p split by truncation + bit-pack (error ~2^-15 rel).
// ---------------------------------------------------------------------------
__global__ __launch_bounds__(512, 2) void attn_kernel(
    const float* __restrict__ x1, const float* __restrict__ x2,
    const float* __restrict__ ga1, const float* __restrict__ ga2,
    const float* __restrict__ ws, float* __restrict__ out_)
{
    const int a = blockIdx.y;
    const float* x = a ? x2 : x1;
    const float gamma = a ? ga2[0] : ga1[0];
    const float* f2 = ws + (size_t)a * WSP;
    const float* gg = f2 + OFF_G;
    const unsigned short* tiles = (const unsigned short*)(f2 + OFF_T);
    float* out = out_ + (size_t)a * ((size_t)64 * N);

    const int m0 = blockIdx.x * 64;
    const int t = threadIdx.x;
    const int w = t >> 6, lane = t & 63;
    const int quad = lane >> 4, l15 = lane & 15;

    // g fragments: lane's 4 m-columns, resident all kernel
    float4 gA[4], gB[4];
    #pragma unroll
    for (int mt = 0; mt < 4; ++mt) {
        const float* gp = gg + (size_t)(m0 + mt*16 + l15) * 8;
        gA[mt] = *(const float4*)gp;
        gB[mt] = *(const float4*)(gp + 4);
    }

    f32x4 acc[4][4];   // [ct][mt]
    #pragma unroll
    for (int i = 0; i < 4; ++i)
        #pragma unroll
        for (int k = 0; k < 4; ++k) acc[i][k] = (f32x4){0.f,0.f,0.f,0.f};

    const int kbeg = w * (N/8);
    const int kend = kbeg + (N/8);

    union BU { bf16x8 v; unsigned u[4]; };

    for (int k0 = kbeg; k0 < kend; k0 += 32) {
        // A fragments: 4 c-tiles, hi+lo
        bf16x8 Ah[4], Al[4];
        {
            const unsigned short* tb = tiles + (size_t)(k0 >> 5) * 4096 + quad*8;
            #pragma unroll
            for (int ct = 0; ct < 4; ++ct) {
                const unsigned short* tc = tb + (ct*16 + l15) * 32;
                Ah[ct] = *(const bf16x8*)tc;
                Al[ct] = *(const bf16x8*)(tc + 2048);
            }
        }
        // B fragments: p = exp2(f.g) in B layout, truncation hi/lo split
        BU bh[4], bl[4];
        {
            const float* fp = f2 + (size_t)(k0 + quad*8) * 8;
            #pragma unroll
            for (int u = 0; u < 4; ++u) {
                const float4 f0a = *(const float4*)(fp + (2*u)*8);
                const float4 f0b = *(const float4*)(fp + (2*u)*8 + 4);
                const float4 f1a = *(const float4*)(fp + (2*u+1)*8);
                const float4 f1b = *(const float4*)(fp + (2*u+1)*8 + 4);
                #pragma unroll
                for (int mt = 0; mt < 4; ++mt) {
                    float s0 = f0a.x*gA[mt].x + f0a.y*gA[mt].y + f0a.z*gA[mt].z + f0a.w*gA[mt].w
                             + f0b.x*gB[mt].x + f0b.y*gB[mt].y + f0b.z*gB[mt].z + f0b.w*gB[mt].w;
                    float s1 = f1a.x*gA[mt].x + f1a.y*gA[mt].y + f1a.z*gA[mt].z + f1a.w*gA[mt].w
                             + f1b.x*gB[mt].x + f1b.y*gB[mt].y + f1b.z*gB[mt].z + f1b.w*gB[mt].w;
                    float p0 = EXP2(s0), p1 = EXP2(s1);
                    unsigned i0 = __float_as_uint(p0), i1 = __float_as_uint(p1);
                    bh[mt].u[u] = (i1 & 0xffff0000u) | (i0 >> 16);
                    float r0 = p0 - __uint_as_float(i0 & 0xffff0000u);
                    float r1 = p1 - __uint_as_float(i1 & 0xffff0000u);
                    bl[mt].u[u] = (__float_as_uint(r1) & 0xffff0000u)
                                | (__float_as_uint(r0) >> 16);
                }
            }
        }
        #pragma unroll
        for (int mt = 0; mt < 4; ++mt) {
            #pragma unroll
            for (int ct = 0; ct < 4; ++ct) {
                acc[ct][mt] = __builtin_amdgcn_mfma_f32_16x16x32_bf16(Ah[ct], bh[mt].v, acc[ct][mt], 0, 0, 0);
                acc[ct][mt] = __builtin_amdgcn_mfma_f32_16x16x32_bf16(Ah[ct], bl[mt].v, acc[ct][mt], 0, 0, 0);
                acc[ct][mt] = __builtin_amdgcn_mfma_f32_16x16x32_bf16(Al[ct], bh[mt].v, acc[ct][mt], 0, 0, 0);
            }
        }
    }

    // cross-wave (K-split) reduction over 8 waves
    __shared__ float red[64][65];
    for (int ww = 0; ww < 8; ++ww) {
        if (w == ww) {
            #pragma unroll
            for (int ct = 0; ct < 4; ++ct)
                #pragma unroll
                for (int mt = 0; mt < 4; ++mt)
                    #pragma unroll
                    for (int r = 0; r < 4; ++r) {
                        int c = ct*16 + quad*4 + r;      // C/D: row=(lane>>4)*4+reg
                        int m = mt*16 + l15;             //      col=lane&15
                        if (ww == 0) red[c][m]  = acc[ct][mt][r];
                        else         red[c][m] += acc[ct][mt][r];
                    }
        }
        __syncthreads();
    }
    #pragma unroll
    for (int i = 0; i < 8; ++i) {
        int e = t + 512*i;
        int c = e >> 6, m = e & 63;
        size_t gi = (size_t)c*N + m0 + m;
        out[gi] = gamma * red[c][m] + x[gi];
    }
}

// ---------------------------------------------------------------------------
extern "C" void kernel_launch(void* const* d_in, const int* in_sizes, int n_in,
                              void* d_out, int out_size, void* d_ws, size_t ws_size,
                              hipStream_t stream)
{
    (void)in_sizes; (void)n_in; (void)out_size; (void)ws_size;
    const float* x1  = (const float*)d_in[0];
    const float* x2  = (const float*)d_in[1];
    const float* Wf  = (const float*)d_in[2];
    const float* bf  = (const float*)d_in[3];
    const float* Wg  = (const float*)d_in[4];
    const float* bg  = (const float*)d_in[5];
    const float* Wh1 = (const float*)d_in[6];
    const float* bh1 = (const float*)d_in[7];
    const float* Wh2 = (const float*)d_in[8];
    const float* bh2 = (const float*)d_in[9];
    const float* g1  = (const float*)d_in[10];
    const float* g2  = (const float*)d_in[11];
    float* out = (float*)d_out;
    float* ws  = (float*)d_ws;

    prep_kernel   <<<dim3(N/64, 2), dim3(256), 0, stream>>>(x1,x2,Wf,bf,Wg,bg,Wh1,bh1,Wh2,bh2,ws);
    rownorm_kernel<<<dim3(N/32, 2), dim3(256), 0, stream>>>(ws);
    attn_kernel   <<<dim3(N/64, 2), dim3(512), 0, stream>>>(x1,x2,g1,g2,ws,out);
}